// Round 7
// baseline (198.597 us; speedup 1.0000x reference)
//
#include <hip/hip_runtime.h>
#include <math.h>

// MMD loss, total = concat(source, target) [8192 x 256] f32.
// L2[i][j] = max(||ti||^2 + ||tj||^2 - 2 ti.tj, 0)
// bandwidth = sum(L2)/(n^2-n)/4, analytic: sum(L2) = 2n*S1 - 2*||sum_i ti||^2
// kernels = sum_{i=0..4} exp(-L2/(bw*2^i + 1e-9))
// outputs: [loss, max(L2), xx, yy, xy, yx]  (6 f32)
//
// Round 7 vs round 6:
//  - gram: double-buffered LDS + prefetch (issue STAGE(seg+1) before compute(seg));
//    the vmcnt(0) drain before each barrier now lands AFTER a full compute phase.
//  - bw_kernel folded into prep (last-block ticket); final folded into gram.
//    Graph: memset + prep + gram (was 5 nodes).

constexpr int NTOT  = 8192;
constexpr int BHALF = 4096;
constexpr int DIM   = 256;
constexpr int BM    = 128;

typedef __attribute__((ext_vector_type(8))) short bf16x8;
typedef __attribute__((ext_vector_type(4))) float f32x4;

#define GLOAD_LDS16(gp, lp)                                                      \
    __builtin_amdgcn_global_load_lds(                                            \
        (__attribute__((address_space(1))) const void*)(gp),                     \
        (__attribute__((address_space(3))) void*)(lp), 16, 0, 0)

// ws layout (bytes):
//   0       : double qsum[4]
//   32      : int    maxBits
//   36      : float  bandwidth
//   40      : int    gramCounter
//   44      : int    prepCounter
//   2112    : float  sq[8192]          (32 KB)
//   36864   : ushort hi[8192*256]      (4 MB, pre-swizzled 512 B rows)
//   4231168 : float  colpart[256][256] (256 KB per-block partial column sums)
//   4493312 : float  sqpart[256]       (1 KB per-block partial sum of sq)

__device__ __forceinline__ int swz(int row, int byteInRow) {
    return (row * 128 + byteInRow) ^ ((row & 7) << 4);
}

__device__ __forceinline__ unsigned short rne_bf16(float f) {
    unsigned u = __float_as_uint(f);
    return (unsigned short)((u + 0x7fffu + ((u >> 16) & 1u)) >> 16);
}

// Fused: row norms (sq), column partial sums, f32 -> bf16 pre-swizzled,
// and (last block) the bandwidth reduction.
__global__ __launch_bounds__(256) void prep_kernel(
        const float* __restrict__ src, const float* __restrict__ tgt,
        float* __restrict__ sq, float* __restrict__ colpart,
        float* __restrict__ sqpart, unsigned short* __restrict__ hi,
        int* __restrict__ prepCounter, float* __restrict__ bwp) {
    __shared__ float  cs[4][256];
    __shared__ float  sblk[256];
    __shared__ double red[256];
    __shared__ unsigned lastFlag;
    const int t = threadIdx.x;
    const int w = t >> 6, l = t & 63;
    const int seg = l >> 4;
    const int b8  = (l * 8) & 127;
    float c0 = 0.f, c1 = 0.f, c2 = 0.f, c3 = 0.f;
    float sqacc = 0.f;

#pragma unroll
    for (int it = 0; it < 8; ++it) {
        const int row = blockIdx.x * 32 + w * 8 + it;
        const float* p = (row < BHALF) ? src + (size_t)row * DIM
                                       : tgt + (size_t)(row - BHALF) * DIM;
        float4 v = reinterpret_cast<const float4*>(p)[l];
        float s = v.x * v.x + v.y * v.y + v.z * v.z + v.w * v.w;
        sqacc += s;
#pragma unroll
        for (int off = 32; off; off >>= 1) s += __shfl_down(s, off);
        if (l == 0) sq[row] = s;
        c0 += v.x; c1 += v.y; c2 += v.z; c3 += v.w;

        unsigned hp0 = (unsigned)rne_bf16(v.x) | ((unsigned)rne_bf16(v.y) << 16);
        unsigned hp1 = (unsigned)rne_bf16(v.z) | ((unsigned)rne_bf16(v.w) << 16);
        const size_t byteoff = (size_t)row * 512 + seg * 128 + (b8 ^ ((row & 7) << 4));
        *reinterpret_cast<uint2*>((char*)hi + byteoff) = make_uint2(hp0, hp1);
    }

    cs[w][l * 4 + 0] = c0; cs[w][l * 4 + 1] = c1;
    cs[w][l * 4 + 2] = c2; cs[w][l * 4 + 3] = c3;
    sblk[t] = sqacc;
    __syncthreads();
    colpart[blockIdx.x * 256 + t] = cs[0][t] + cs[1][t] + cs[2][t] + cs[3][t];
    for (int off = 128; off; off >>= 1) {
        if (t < off) sblk[t] += sblk[t + off];
        __syncthreads();
    }
    if (t == 0) sqpart[blockIdx.x] = sblk[0];

    // ---- last block reduces bandwidth ----
    __threadfence();
    if (t == 0) lastFlag = (atomicAdd(prepCounter, 1) == (NTOT / 32 - 1)) ? 1u : 0u;
    __syncthreads();
    if (lastFlag) {
        __threadfence();
        double v = 0.0;
        for (int b = 0; b < 256; ++b) v += (double)colpart[b * 256 + t];
        red[t] = v * v; __syncthreads();
        for (int off = 128; off; off >>= 1) {
            if (t < off) red[t] += red[t + off];
            __syncthreads();
        }
        double V2 = red[0]; __syncthreads();
        red[t] = (double)sqpart[t]; __syncthreads();
        for (int off = 128; off; off >>= 1) {
            if (t < off) red[t] += red[t + off];
            __syncthreads();
        }
        if (t == 0) {
            double S1 = red[0];
            const double n = (double)NTOT;
            double sumL2 = 2.0 * n * S1 - 2.0 * V2;
            *bwp = (float)(sumL2 / (n * n - n) / 4.0);
        }
    }
}

__global__ __launch_bounds__(256) void gram_kernel(
        const unsigned short* __restrict__ hi,
        const float* __restrict__ sq, const float* __restrict__ bwp,
        double* __restrict__ qsum, int* __restrict__ maxBits,
        int* __restrict__ gramCounter, float* __restrict__ out) {
    // XCD-aware swizzle over the 2080-block upper triangle (2080 = 8*260)
    const int tb = blockIdx.x;
    const int id = (tb & 7) * 260 + (tb >> 3);
    int k = 2079 - id;
    int u = (int)((sqrt((double)(8 * k + 1)) - 1.0) * 0.5);
    while ((u + 1) * (u + 2) / 2 <= k) ++u;
    while (u * (u + 1) / 2 > k) --u;
    const int by = 63 - u;
    const int bx = 63 - (k - u * (u + 1) / 2);
    const bool diag = (bx == by);

    __shared__ alignas(16) char ldsA[2][BM * 128];   // 2 x 16 KB
    __shared__ alignas(16) char ldsB[2][BM * 128];   // 2 x 16 KB
    __shared__ double sred[4];
    __shared__ float  mred[4];
    __shared__ unsigned lastFlag;

    const int i0 = by * BM;
    const int j0 = bx * BM;
    const char* Ahi = (const char*)hi + (size_t)i0 * 512;
    const char* Bhi = (const char*)hi + (size_t)j0 * 512;

    const int t    = threadIdx.x;
    const int lane = t & 63;
    const int w    = t >> 6;       // 4 waves, 2x2 over the 128x128 tile
    const int wr   = w >> 1;
    const int wc   = w & 1;
    const int lrow = lane & 15;

    f32x4 acc[4][4] = {};

    auto STAGE = [&](int seg, int buf) {
#pragma unroll
        for (int it = 0; it < 4; ++it) {
            const int chunk = it * 4 + w;              // wave-uniform
            const int o     = chunk * 1024 + lane * 16;
            const int row   = o >> 7;
            const size_t srcoff = (size_t)row * 512 + seg * 128 + (o & 127);
            GLOAD_LDS16(Ahi + srcoff, &ldsA[buf][chunk * 1024]);
            if (!diag) GLOAD_LDS16(Bhi + srcoff, &ldsB[buf][chunk * 1024]);
        }
    };

    STAGE(0, 0);
    __syncthreads();                               // vmcnt(0) drain (compiler)

#pragma unroll
    for (int seg = 0; seg < 4; ++seg) {            // 4 K-chunks of 64 bf16
        if (seg < 3) STAGE(seg + 1, (seg + 1) & 1);   // prefetch next FIRST
        const char* abuf = ldsA[seg & 1];
        const char* bbuf = diag ? ldsA[seg & 1] : ldsB[seg & 1];
#pragma unroll
        for (int ks = 0; ks < 2; ++ks) {
            const int kb = ks * 64 + (lane >> 4) * 16;
            bf16x8 a[4], b[4];
#pragma unroll
            for (int mt = 0; mt < 4; ++mt)
                a[mt] = *reinterpret_cast<const bf16x8*>(
                    abuf + swz(wr * 64 + mt * 16 + lrow, kb));
#pragma unroll
            for (int nt = 0; nt < 4; ++nt)
                b[nt] = *reinterpret_cast<const bf16x8*>(
                    bbuf + swz(wc * 64 + nt * 16 + lrow, kb));
#pragma unroll
            for (int mt = 0; mt < 4; ++mt)
#pragma unroll
                for (int nt = 0; nt < 4; ++nt)
                    acc[mt][nt] = __builtin_amdgcn_mfma_f32_16x16x32_bf16(
                        a[mt], b[nt], acc[mt][nt], 0, 0, 0);
        }
        __syncthreads();   // drains prefetch loads (overlapped with compute above)
    }

    // ---- epilogue: L2, max, 5-kernel exp sum via squaring chain ----
    const float bw  = *bwp;
    const float ic4 = -1.44269504088896340736f / (bw * 16.0f + 1e-9f);

    float m = 0.0f;
    float ksum = 0.0f;
    const int rbase = i0 + wr * 64 + (lane >> 4) * 4;
    const int cbase = j0 + wc * 64 + lrow;
    float sb[4];
#pragma unroll
    for (int nt = 0; nt < 4; ++nt) sb[nt] = sq[cbase + nt * 16];
#pragma unroll
    for (int mt = 0; mt < 4; ++mt) {
        float sa[4];
#pragma unroll
        for (int r = 0; r < 4; ++r) sa[r] = sq[rbase + mt * 16 + r];
#pragma unroll
        for (int nt = 0; nt < 4; ++nt)
#pragma unroll
            for (int r = 0; r < 4; ++r) {
                float l2 = fmaxf(fmaf(-2.0f, acc[mt][nt][r], sa[r] + sb[nt]), 0.0f);
                m = fmaxf(m, l2);
                float e1  = exp2f(l2 * ic4);
                float e2  = e1 * e1;
                float e4  = e2 * e2;
                float e8  = e4 * e4;
                float e16 = e8 * e8;
                ksum += (e1 + e2) + (e4 + e8) + e16;
            }
    }

    double s = (double)ksum;
#pragma unroll
    for (int off = 32; off; off >>= 1) {
        s += __shfl_down(s, off);
        m  = fmaxf(m, __shfl_down(m, off));
    }
    if ((t & 63) == 0) { sred[w] = s; mred[w] = m; }
    __syncthreads();
    if (t == 0) {
        double st = sred[0] + sred[1] + sred[2] + sred[3];
        float  mt = fmaxf(fmaxf(mred[0], mred[1]), fmaxf(mred[2], mred[3]));
        atomicMax(maxBits, __float_as_int(mt));
        const int q  = (((i0 >= BHALF) ? 2 : 0) | ((j0 >= BHALF) ? 1 : 0));
        const int qT = (((j0 >= BHALF) ? 2 : 0) | ((i0 >= BHALF) ? 1 : 0));
        if (diag) {
            atomicAdd(&qsum[q], st);
        } else if (q == qT) {
            atomicAdd(&qsum[q], 2.0 * st);       // mirror lower triangle
        } else {
            atomicAdd(&qsum[q],  st);
            atomicAdd(&qsum[qT], st);
        }
        __threadfence();
        lastFlag = (atomicAdd(gramCounter, 1) == 2079) ? 1u : 0u;
    }
    __syncthreads();
    if (lastFlag && t == 0) {
        __threadfence();
        // atomic-RMW reads for cross-XCD-coherent values
        double xx = atomicAdd(&qsum[0], 0.0);
        double xy = atomicAdd(&qsum[1], 0.0);
        double yx = atomicAdd(&qsum[2], 0.0);
        double yy = atomicAdd(&qsum[3], 0.0);
        int    mb = atomicMax(maxBits, 0);
        const double denom = (double)BHALF * (double)BHALF;
        xx /= denom; xy /= denom; yx /= denom; yy /= denom;
        out[0] = (float)(xx + yy - xy - yx);
        out[1] = __int_as_float(mb);
        out[2] = (float)xx;
        out[3] = (float)yy;
        out[4] = (float)xy;
        out[5] = (float)yx;
    }
}

extern "C" void kernel_launch(void* const* d_in, const int* in_sizes, int n_in,
                              void* d_out, int out_size, void* d_ws, size_t ws_size,
                              hipStream_t stream) {
    const float* src = (const float*)d_in[0];
    const float* tgt = (const float*)d_in[1];
    float* out = (float*)d_out;

    double* qsum     = (double*)d_ws;
    int*    maxB     = (int*)   ((char*)d_ws + 32);
    float*  bwp      = (float*) ((char*)d_ws + 36);
    int*    gramCnt  = (int*)   ((char*)d_ws + 40);
    int*    prepCnt  = (int*)   ((char*)d_ws + 44);
    float*  sq       = (float*) ((char*)d_ws + 2112);
    unsigned short* hi = (unsigned short*)((char*)d_ws + 36864);
    float*  colpart  = (float*) ((char*)d_ws + 36864 + (size_t)NTOT * DIM * 2);
    float*  sqpart   = (float*) ((char*)d_ws + 36864 + (size_t)NTOT * DIM * 2 + 256 * 256 * 4);

    hipMemsetAsync(d_ws, 0, 64, stream);

    prep_kernel<<<NTOT / 32, 256, 0, stream>>>(src, tgt, sq, colpart, sqpart, hi,
                                               prepCnt, bwp);
    gram_kernel<<<2080, 256, 0, stream>>>(hi, sq, bwp, qsum, maxB, gramCnt, out);
}